// Round 1
// 2796.536 us; speedup vs baseline: 1.2203x; 1.2203x over previous
//
#include <hip/hip_runtime.h>
#include <cstdint>
#include <cstddef>

#define B_    256
#define Q_    512
#define D_    32
#define H_    192
#define HID_  384
#define INCH_ 96
#define M_    (B_*Q_)    // 131072
#define WOUT_ 64
#define BPB   4          // batches per rollout block (== quarters)
#define RT_   768        // rollout threads: 4 quarters x 192, 12 waves
#define PI_F  3.14159265358979323846f

typedef unsigned int uint_t;

__device__ __forceinline__ float sigm(float x){ return 1.f/(1.f+expf(-x)); }
__device__ __forceinline__ float gelu_exact(float x){ return 0.5f*x*(1.f+erff(x*0.7071067811865475f)); }
__device__ __forceinline__ void fma4(float4& a, float s, const float4& v){
  a.x += s*v.x; a.y += s*v.y; a.z += s*v.z; a.w += s*v.w;
}

// ---------------- features: [x, dy, ddy] ----------------
__global__ void feats_kernel(const float* __restrict__ x, float* __restrict__ feats, int nrows){
  int idx = blockIdx.x*256 + threadIdx.x;
  if (idx >= nrows*32) return;
  int d  = idx & 31;
  int bt = idx >> 5;
  int t  = bt & 511;
  const float* xr = x + (size_t)bt*D_;
  float xc  = xr[d];
  float xm1 = (t>0) ? xr[d - D_]   : 0.f;
  float xm2 = (t>1) ? xr[d - 2*D_] : 0.f;
  float dy   = (t>0) ? xc - xm1   : 0.f;
  float dym1 = (t>1) ? xm1 - xm2  : 0.f;
  float ddy  = (t>0) ? dy - dym1  : 0.f;
  float* fr = feats + (size_t)bt*INCH_;
  fr[d] = xc; fr[D_+d] = dy; fr[2*D_+d] = ddy;
}

// ---------------- 64x64x8 fp32 tiled GEMM, 4 blocks/CU ----------------
// MODE 0: out = acc+bias ; MODE 1: out = gelu(acc+bias) ; MODE 2: A affine, C += acc+bias
template<int MODE>
__global__ __launch_bounds__(256,4) void gemm_t64(
    const float* __restrict__ Af,
    const float* __restrict__ W,  const float* __restrict__ bias,
    float* __restrict__ Cf,
    const float* __restrict__ scale, const float* __restrict__ grnb,
    int N, int K)
{
  __shared__ float As[8][64];
  __shared__ float Bs[8][64];
  const int tid = threadIdx.x;
  const int bm = blockIdx.x*64, bn = blockIdx.y*64;
  const int tx = tid & 15, ty = tid >> 4;
  const int lrow = (tid & 127) >> 1, lk = (tid & 1)*4;
  const bool isA = tid < 128;
  const float* srow = (MODE==2) ? (scale + (size_t)(bm>>9)*HID_) : nullptr;

  float acc[4][4];
  #pragma unroll
  for (int i=0;i<4;i++)
    #pragma unroll
    for (int j=0;j<4;j++) acc[i][j]=0.f;

  const float* gsrc = isA ? (Af + (size_t)(bm+lrow)*K) : (W + (size_t)(bn+lrow)*K);

  for (int k0=0;k0<K;k0+=8){
    float4 v = *(const float4*)(gsrc + k0 + lk);
    if (MODE==2 && isA){
      int c = k0+lk;
      float4 sc = *(const float4*)(srow+c);
      float4 gb = *(const float4*)(grnb+c);
      v.x = v.x*sc.x+gb.x; v.y = v.y*sc.y+gb.y;
      v.z = v.z*sc.z+gb.z; v.w = v.w*sc.w+gb.w;
    }
    if (isA){
      As[lk+0][lrow]=v.x; As[lk+1][lrow]=v.y; As[lk+2][lrow]=v.z; As[lk+3][lrow]=v.w;
    } else {
      Bs[lk+0][lrow]=v.x; Bs[lk+1][lrow]=v.y; Bs[lk+2][lrow]=v.z; Bs[lk+3][lrow]=v.w;
    }
    __syncthreads();
    #pragma unroll
    for (int kk=0;kk<8;kk++){
      float4 a = *(const float4*)&As[kk][ty*4];
      float4 b = *(const float4*)&Bs[kk][tx*4];
      float ar[4] = {a.x,a.y,a.z,a.w};
      #pragma unroll
      for (int i=0;i<4;i++){
        acc[i][0] += ar[i]*b.x; acc[i][1] += ar[i]*b.y;
        acc[i][2] += ar[i]*b.z; acc[i][3] += ar[i]*b.w;
      }
    }
    __syncthreads();
  }

  const int o0 = bn + tx*4;
  float4 b0 = *(const float4*)(bias + o0);
  #pragma unroll
  for (int i=0;i<4;i++){
    int m = bm + ty*4 + i;
    if (MODE==0){
      float4 v; v.x=acc[i][0]+b0.x; v.y=acc[i][1]+b0.y; v.z=acc[i][2]+b0.z; v.w=acc[i][3]+b0.w;
      *(float4*)(Cf + (size_t)m*N + o0) = v;
    } else if (MODE==1){
      float4 v;
      v.x = gelu_exact(acc[i][0]+b0.x); v.y = gelu_exact(acc[i][1]+b0.y);
      v.z = gelu_exact(acc[i][2]+b0.z); v.w = gelu_exact(acc[i][3]+b0.w);
      *(float4*)(Cf + (size_t)m*N + o0) = v;
    } else {
      float4 old = *(const float4*)(Cf + (size_t)m*N + o0);
      float4 v; v.x=old.x+acc[i][0]+b0.x; v.y=old.y+acc[i][1]+b0.y;
      v.z=old.z+acc[i][2]+b0.z; v.w=old.w+acc[i][3]+b0.w;
      *(float4*)(Cf + (size_t)m*N + o0) = v;
    }
  }
}

// ---------------- depthwise conv (k=9, edge pad) + LN, 4 timesteps per block ----------------
__global__ __launch_bounds__(192) void dwconv_ln4(
  const float* __restrict__ h, const float* __restrict__ dww, const float* __restrict__ dwb,
  const float* __restrict__ lnw, const float* __restrict__ lnb, float* __restrict__ yln)
{
  __shared__ float sh[12][192];
  __shared__ float rs_[192], rq_[192], st[2];
  const int c  = threadIdx.x;
  const int t0 = (blockIdx.x & 127) * 4;
  const size_t base = (size_t)(blockIdx.x >> 7) * Q_ * H_;
  #pragma unroll
  for (int r=0;r<12;r++){
    int tt = t0 - 4 + r; tt = tt<0?0:(tt>511?511:tt);
    sh[r][c] = h[base + (size_t)tt*H_ + c];
  }
  float w[9];
  #pragma unroll
  for (int k=0;k<9;k++) w[k] = dww[c*9+k];
  const float dbias = dwb[c], lw = lnw[c], lb = lnb[c];
  __syncthreads();
  for (int i=0;i<4;i++){
    float acc = dbias;
    #pragma unroll
    for (int k=0;k<9;k++) acc += w[k]*sh[i+k][c];
    rs_[c]=acc; rq_[c]=acc*acc;
    __syncthreads();
    if (c < 64){
      float s = rs_[c]+rs_[c+64]+rs_[c+128];
      float q = rq_[c]+rq_[c+64]+rq_[c+128];
      #pragma unroll
      for (int off=32; off>0; off>>=1){ s += __shfl_down(s,off); q += __shfl_down(q,off); }
      if (c==0){ st[0]=s; st[1]=q; }
    }
    __syncthreads();
    float mean = st[0]*(1.f/H_);
    float var  = st[1]*(1.f/H_) - mean*mean;
    float r = rsqrtf(var + 1e-5f);
    yln[base + (size_t)(t0+i)*H_ + c] = (acc-mean)*r*lw + lb;
  }
}

// ---------------- output LayerNorm (+ save last-timestep row) ----------------
__global__ __launch_bounds__(192) void out_ln_kernel(
  const float* __restrict__ h, const float* __restrict__ lnw, const float* __restrict__ lnb,
  float* __restrict__ o, float* __restrict__ hlast, int b0)
{
  __shared__ float rs_[192], rq_[192], st[2];
  const int c  = threadIdx.x;
  const int bt = blockIdx.x;
  float v = h[(size_t)bt*H_ + c];
  rs_[c]=v; rq_[c]=v*v;
  __syncthreads();
  if (c < 64){
    float s = rs_[c]+rs_[c+64]+rs_[c+128];
    float q = rq_[c]+rq_[c+64]+rq_[c+128];
    #pragma unroll
    for (int off=32; off>0; off>>=1){ s += __shfl_down(s,off); q += __shfl_down(q,off); }
    if (c==0){ st[0]=s; st[1]=q; }
  }
  __syncthreads();
  float mean = st[0]*(1.f/H_);
  float var  = st[1]*(1.f/H_) - mean*mean;
  float r = rsqrtf(var + 1e-5f);
  float res = (v-mean)*r*lnw[c] + lnb[c];
  o[(size_t)bt*H_ + c] = res;
  if ((bt & 511) == 511) hlast[(size_t)(b0 + (bt>>9))*H_ + c] = res;
}

// ---------------- GRN stats ----------------
__global__ __launch_bounds__(384) void grn_stats_kernel(
  const float* __restrict__ y1, const float* __restrict__ grn_g, float* __restrict__ scale)
{
  __shared__ float r[384];
  const int c = threadIdx.x;
  const int b = blockIdx.x;
  const float* p = y1 + (size_t)b*Q_*HID_ + c;
  float s = 0.f;
  #pragma unroll 8
  for (int t=0;t<Q_;t++){ float v = p[(size_t)t*HID_]; s += v*v; }
  float gx = sqrtf(s);
  r[c] = gx;
  __syncthreads();
  if (c < 64){
    float v = r[c]+r[c+64]+r[c+128]+r[c+192]+r[c+256]+r[c+320];
    #pragma unroll
    for (int off=32; off>0; off>>=1) v += __shfl_down(v,off);
    if (c==0) r[0]=v;
  }
  __syncthreads();
  float mean = r[0]*(1.f/HID_);
  scale[(size_t)b*HID_ + c] = 1.f + grn_g[c]*gx/(mean + 1e-6f);
}

// ---------------- pack fc_rp / fc_gain into padded (64,192) W ----------------
__global__ void pack_w_kernel(const float* __restrict__ frw, const float* __restrict__ frb,
                              const float* __restrict__ fgw, const float* __restrict__ fgb,
                              float* __restrict__ w_pad, float* __restrict__ b_pad)
{
  int idx = blockIdx.x*256 + threadIdx.x;
  if (idx >= 64*192) return;
  int o = idx / 192, k = idx % 192;
  float v = 0.f;
  if (o < 2) v = frw[o*192+k]; else if (o < 34) v = fgw[(o-2)*192+k];
  w_pad[idx] = v;
  if (k == 0){
    float bv = 0.f;
    if (o < 2) bv = frb[o]; else if (o < 34) bv = fgb[o-2];
    b_pad[o] = bv;
  }
}

// ---------------- wide Kalman prep ----------------
__global__ void kalman_prep_kernel(const float* __restrict__ raw, float* __restrict__ rp, int nrows){
  int idx = blockIdx.x*256 + threadIdx.x;
  if (idx >= nrows*32) return;
  int d  = idx & 31;
  int bt = idx >> 5;
  const float* r = raw + (size_t)bt*64;
  float* o = rp + (size_t)bt*34;
  o[2+d] = sigm(r[2+d]);
  if (d==0){
    float rho = 1.25f*sigm(r[0]);
    float phi = PI_F * tanhf(r[1]);
    o[0] = rho*cosf(phi);
    o[1] = rho*sinf(phi);
  }
}

// ---------------- sequential Kalman scan (FMA-only) ----------------
__global__ __launch_bounds__(64) void kalman_scan_kernel(
  const float* __restrict__ x_c, const float* __restrict__ rp, float* __restrict__ xpost,
  int b0, int Bc)
{
  const int lane = threadIdx.x;
  const int bl = blockIdx.x*4 + (lane>>4);
  if (bl >= Bc) return;
  const int m = lane & 15;
  const float* xb  = x_c + (size_t)bl*Q_*D_;
  const float* rpb = rp  + (size_t)bl*Q_*34;
  float re = xb[m], im = xb[16+m];
  for (int t=0;t<Q_;t++){
    const float* r = rpb + (size_t)t*34;
    float rc = r[0], rs = r[1];
    float g0 = r[2+m], g1 = r[18+m];
    float y0 = xb[(size_t)t*D_ + m], y1v = xb[(size_t)t*D_ + 16 + m];
    float pr  = rc*re - rs*im;
    float pim = rs*re + rc*im;
    re = pr  + g0*(y0  - pr);
    im = pim + g1*(y1v - pim);
  }
  xpost[(b0+bl)*D_ + m] = re;
  xpost[(b0+bl)*D_ + 16 + m] = im;
}

// ---------------- rollout weight prep: wT1[k][o] + packed [k][o][8] gate block ----------------
__global__ void prep_rollout_kernel(const float* __restrict__ riw, const float* __restrict__ wih,
                                    const float* __restrict__ whh,
                                    float* __restrict__ wT1, float* __restrict__ wPack)
{
  int idx = blockIdx.x*256 + threadIdx.x;
  if (idx < 224*192){
    int o = idx % 192, k = idx / 192;
    wT1[idx] = riw[o*224 + k];
    return;
  }
  idx -= 224*192;
  if (idx < 192*192){
    int o = idx % 192, k = idx / 192;
    float* w = wPack + ((size_t)k*192 + o)*8;
    w[0] = wih[(0*192+o)*192 + k];
    w[1] = wih[(1*192+o)*192 + k];
    w[2] = wih[(2*192+o)*192 + k];
    w[3] = whh[(0*192+o)*192 + k];
    w[4] = whh[(1*192+o)*192 + k];
    w[5] = whh[(2*192+o)*192 + k];
    w[6] = 0.f; w[7] = 0.f;
  }
}

// ---------------- GRU rollout: 4 quarters x 192 threads, 4-way split-K ----------------
// quarter q (3 waves each, wave-aligned) owns batch q for the combine/LN/Kalman tail.
// LDS state is batch-major (hT/xT/cT[k][4]) so one ds_read_b128 broadcast feeds 4 batches.
// Partials are gate-major (pA/pB[quarter][slot][o]) -> stride-1 across lanes, conflict-free.
__global__ __launch_bounds__(RT_) void rollout_kernel(
  const float* __restrict__ hlast, const float* __restrict__ xpost,
  const float* __restrict__ wT1,  const float* __restrict__ rib_,
  const float* __restrict__ wPack,
  const float* __restrict__ bih,  const float* __restrict__ bhh,
  const float* __restrict__ lnw,  const float* __restrict__ lnb,
  const float* __restrict__ frw,  const float* __restrict__ frb,
  float* __restrict__ out)
{
  const int tid = threadIdx.x;
  const int q   = tid / 192;        // quarter 0..3
  const int o   = tid - q*192;      // output channel 0..191
  const int bb  = blockIdx.x*BPB;

  __shared__ float hT[192][4];      // h state, batch-major
  __shared__ float xT[192][4];      // x = tanh(W1 [h;c]) , batch-major
  __shared__ float cT[32][4];       // curr (Kalman state), batch-major
  __shared__ float pA[4][4][192];   // phase-A partials [quarter][batch][o]
  __shared__ float pB[4][24][192];  // phase-B partials [quarter][batch*6+gate][o]
  __shared__ float red1[4][192], red2[4][192];
  __shared__ float stL[4][2], stR[4][2];

  // init state
  hT[o][q] = hlast[(size_t)(bb+q)*H_ + o];
  if (o < 32) cT[o][q] = xpost[(bb+q)*D_ + o];

  const float w_ln = lnw[o], b_ln = lnb[o];
  const float w_r0 = frw[o], w_r1 = frw[192+o];
  const float fb0 = frb[0],  fb1 = frb[1];
  const float bi0 = bih[o], bi1 = bih[192+o], bi2 = bih[384+o];
  const float bh0 = bhh[o], bh1 = bhh[192+o], bh2 = bhh[384+o];
  const float rib = rib_[o];
  __syncthreads();

  for (int s=0; s<WOUT_; s++){
    // ---- phase A: partial x = W1 @ [h;c], K=224 split 4-way (56 each) ----
    float a0=0.f, a1=0.f, a2=0.f, a3=0.f;
    if (q < 3){
      const int k0 = 56*q;
      #pragma unroll 4
      for (int i=0;i<56;i++){
        const int k = k0+i;
        const float w  = wT1[k*192+o];
        const float4 h4 = *(const float4*)&hT[k][0];
        a0 += w*h4.x; a1 += w*h4.y; a2 += w*h4.z; a3 += w*h4.w;
      }
    } else {
      #pragma unroll 4
      for (int i=0;i<24;i++){
        const int k = 168+i;
        const float w  = wT1[k*192+o];
        const float4 h4 = *(const float4*)&hT[k][0];
        a0 += w*h4.x; a1 += w*h4.y; a2 += w*h4.z; a3 += w*h4.w;
      }
      #pragma unroll 4
      for (int i=0;i<32;i++){
        const float w  = wT1[(192+i)*192+o];
        const float4 c4 = *(const float4*)&cT[i][0];
        a0 += w*c4.x; a1 += w*c4.y; a2 += w*c4.z; a3 += w*c4.w;
      }
    }
    pA[q][0][o]=a0; pA[q][1][o]=a1; pA[q][2][o]=a2; pA[q][3][o]=a3;
    __syncthreads();

    // x combine: thread (q,o) owns batch q, channel o
    xT[o][q] = tanhf(rib + pA[0][q][o] + pA[1][q][o] + pA[2][q][o] + pA[3][q][o]);
    __syncthreads();

    // ---- phase B: partial gates, K=192 split 4-way (48 each) ----
    float4 A0 = make_float4(0.f,0.f,0.f,0.f);
    float4 A1=A0, A2=A0, B0=A0, B1=A0, B2=A0;
    const int kb = 48*q;
    #pragma unroll 4
    for (int i=0;i<48;i++){
      const int k = kb+i;
      const float4* wp = (const float4*)(wPack + ((size_t)k*192 + o)*8);
      const float4 wA = wp[0];
      const float4 wB = wp[1];
      const float4 xx = *(const float4*)&xT[k][0];
      const float4 hh = *(const float4*)&hT[k][0];
      fma4(A0, wA.x, xx); fma4(A1, wA.y, xx); fma4(A2, wA.z, xx);
      fma4(B0, wA.w, hh); fma4(B1, wB.x, hh); fma4(B2, wB.y, hh);
    }
    pB[q][ 0][o]=A0.x; pB[q][ 1][o]=A1.x; pB[q][ 2][o]=A2.x;
    pB[q][ 3][o]=B0.x; pB[q][ 4][o]=B1.x; pB[q][ 5][o]=B2.x;
    pB[q][ 6][o]=A0.y; pB[q][ 7][o]=A1.y; pB[q][ 8][o]=A2.y;
    pB[q][ 9][o]=B0.y; pB[q][10][o]=B1.y; pB[q][11][o]=B2.y;
    pB[q][12][o]=A0.z; pB[q][13][o]=A1.z; pB[q][14][o]=A2.z;
    pB[q][15][o]=B0.z; pB[q][16][o]=B1.z; pB[q][17][o]=B2.z;
    pB[q][18][o]=A0.w; pB[q][19][o]=A1.w; pB[q][20][o]=A2.w;
    pB[q][21][o]=B0.w; pB[q][22][o]=B1.w; pB[q][23][o]=B2.w;
    __syncthreads();

    // ---- gate combine for batch q ----
    const int g6 = q*6;
    float P0 = bi0 + pB[0][g6+0][o]+pB[1][g6+0][o]+pB[2][g6+0][o]+pB[3][g6+0][o];
    float P1 = bi1 + pB[0][g6+1][o]+pB[1][g6+1][o]+pB[2][g6+1][o]+pB[3][g6+1][o];
    float P2 = bi2 + pB[0][g6+2][o]+pB[1][g6+2][o]+pB[2][g6+2][o]+pB[3][g6+2][o];
    float Q0 = bh0 + pB[0][g6+3][o]+pB[1][g6+3][o]+pB[2][g6+3][o]+pB[3][g6+3][o];
    float Q1 = bh1 + pB[0][g6+4][o]+pB[1][g6+4][o]+pB[2][g6+4][o]+pB[3][g6+4][o];
    float Q2 = bh2 + pB[0][g6+5][o]+pB[1][g6+5][o]+pB[2][g6+5][o]+pB[3][g6+5][o];
    float rg = sigm(P0+Q0), zz = sigm(P1+Q1);
    float nn = tanhf(P2 + rg*Q2);
    float pre = (1.f-zz)*nn + zz*hT[o][q];
    red1[q][o] = pre; red2[q][o] = pre*pre;
    __syncthreads();

    // ---- LN stats: wave 3q reduces batch q ----
    if (o < 64){
      float s1 = red1[q][o]+red1[q][o+64]+red1[q][o+128];
      float s2 = red2[q][o]+red2[q][o+64]+red2[q][o+128];
      #pragma unroll
      for (int off=32; off>0; off>>=1){ s1 += __shfl_down(s1,off); s2 += __shfl_down(s2,off); }
      if (o==0){ stL[q][0]=s1; stL[q][1]=s2; }
    }
    __syncthreads();

    const float inv = 1.f/192.f;
    float mu  = stL[q][0]*inv;
    float var = stL[q][1]*inv - mu*mu;
    float hn  = (pre-mu)*rsqrtf(var+1e-5f)*w_ln + b_ln;
    hT[o][q]  = hn;
    red1[q][o] = hn*w_r0; red2[q][o] = hn*w_r1;
    __syncthreads();

    // ---- rho/phi projections: wave 3q reduces batch q ----
    if (o < 64){
      float s1 = red1[q][o]+red1[q][o+64]+red1[q][o+128];
      float s2 = red2[q][o]+red2[q][o+64]+red2[q][o+128];
      #pragma unroll
      for (int off=32; off>0; off>>=1){ s1 += __shfl_down(s1,off); s2 += __shfl_down(s2,off); }
      if (o==0){ stR[q][0]=s1; stR[q][1]=s2; }
    }
    __syncthreads();

    // ---- Kalman rotate + output: 16 lanes per quarter ----
    if (o < 16){
      float rho = 1.25f*sigm(stR[q][0]+fb0);
      float phi = PI_F*tanhf(stR[q][1]+fb1);
      float rc = rho*cosf(phi), rs = rho*sinf(phi);
      float re = cT[o][q], im = cT[o+16][q];
      float nre = rc*re - rs*im;
      float nim = rs*re + rc*im;
      cT[o][q] = nre; cT[o+16][q] = nim;
      float* ob = out + ((size_t)(bb+q)*WOUT_ + s)*D_;
      ob[o] = nre; ob[o+16] = nim;
    }
    __syncthreads();
  }
}

// ---------------- host launch ----------------
extern "C" void kernel_launch(void* const* d_in, const int* in_sizes, int n_in,
                              void* d_out, int out_size, void* d_ws, size_t ws_size,
                              hipStream_t stream)
{
  const float* x_in     = (const float*)d_in[0];
  const float* inp_w    = (const float*)d_in[1];
  const float* inp_b    = (const float*)d_in[2];
  const float* b_dw_w   = (const float*)d_in[3];
  const float* b_dw_b   = (const float*)d_in[4];
  const float* b_ln_w   = (const float*)d_in[5];
  const float* b_ln_b   = (const float*)d_in[6];
  const float* b_pw1_w  = (const float*)d_in[7];
  const float* b_pw1_b  = (const float*)d_in[8];
  const float* b_grn_g  = (const float*)d_in[9];
  const float* b_grn_b  = (const float*)d_in[10];
  const float* b_pw2_w  = (const float*)d_in[11];
  const float* b_pw2_b  = (const float*)d_in[12];
  const float* out_ln_w = (const float*)d_in[13];
  const float* out_ln_b = (const float*)d_in[14];
  const float* fc_rp_w  = (const float*)d_in[15];
  const float* fc_rp_b  = (const float*)d_in[16];
  const float* fc_gain_w= (const float*)d_in[17];
  const float* fc_gain_b= (const float*)d_in[18];
  const float* roll_in_w= (const float*)d_in[19];
  const float* roll_in_b= (const float*)d_in[20];
  const float* gru_wih  = (const float*)d_in[21];
  const float* gru_whh  = (const float*)d_in[22];
  const float* gru_bih  = (const float*)d_in[23];
  const float* gru_bhh  = (const float*)d_in[24];
  const float* roll_ln_w= (const float*)d_in[25];
  const float* roll_ln_b= (const float*)d_in[26];
  const float* fc_rp_r_w= (const float*)d_in[27];
  const float* fc_rp_r_b= (const float*)d_in[28];
  float* out = (float*)d_out;

  // ---- adaptive chunking ----
  // per-row floats: h(192) + yln(192) + mid(384; feats/y1, then rpraw(64)+rp(34)) = 768
  // fixed tail: scaleB 98304 + w_pad 12288 + b_pad 64 + xpost 8192 + hlast 49152
  //           + wT1 43008 + wPack 294912 = 505920 ; + margin
  const size_t SMAL_FLOATS = 505920 + 4096;
  size_t ws_floats = ws_size / 4;
  int nchunk = 256;
  const int cand[9] = {1,2,4,8,16,32,64,128,256};
  for (int ci=0; ci<9; ci++){
    size_t Mc_try = (size_t)M_ / cand[ci];
    if (Mc_try*768 + SMAL_FLOATS <= ws_floats){ nchunk = cand[ci]; break; }
  }
  const int    Bc = B_ / nchunk;
  const size_t Mc = (size_t)Bc * Q_;

  float* ws    = (float*)d_ws;
  float* h_c   = ws;
  float* yln_c = h_c   + Mc*192;
  float* mid_c = yln_c + Mc*192;
  float* smal  = mid_c + Mc*384;

  float* feats_c = mid_c;
  float* y1_c    = mid_c;
  float* rpraw   = mid_c;                // Mc*64 (y1 dead by then)
  float* rp_c    = mid_c + Mc*64;        // Mc*34

  float* scaleB = smal;                  // Bc*384 (reserve 98304)
  float* w_pad  = smal + 98304;          // 64*192
  float* b_pad  = w_pad + 12288;         // 64
  float* xpost  = b_pad + 64;            // B_*32
  float* hlast  = xpost + 8192;          // B_*192
  float* wT1    = hlast + 49152;         // 224*192
  float* wPack  = wT1 + 43008;           // 192*192*8

  // one-time weight prep
  pack_w_kernel<<<(64*192+255)/256, 256, 0, stream>>>(fc_rp_w, fc_rp_b, fc_gain_w, fc_gain_b, w_pad, b_pad);
  prep_rollout_kernel<<<(224*192+192*192+255)/256, 256, 0, stream>>>(roll_in_w, gru_wih, gru_whh, wT1, wPack);

  const int gmx = (int)(Mc/64);
  for (int ch=0; ch<nchunk; ch++){
    const float* x_c = x_in + (size_t)ch*Mc*D_;
    // 1. features + input projection
    feats_kernel<<<(int)((Mc*32+255)/256), 256, 0, stream>>>(x_c, feats_c, (int)Mc);
    gemm_t64<0><<<dim3(gmx, 3), 256, 0, stream>>>(feats_c, inp_w, inp_b,
                                                  h_c, nullptr, nullptr, H_, INCH_);
    // 2. ConvNeXt blocks
    for (int blk = 0; blk < 2; blk++){
      const float* dww = b_dw_w + blk*H_*9;     const float* dwb = b_dw_b + blk*H_;
      const float* lnw = b_ln_w + blk*H_;       const float* lnb = b_ln_b + blk*H_;
      const float* p1w = b_pw1_w + blk*HID_*H_; const float* p1b = b_pw1_b + blk*HID_;
      const float* gg  = b_grn_g + blk*HID_;    const float* gb  = b_grn_b + blk*HID_;
      const float* p2w = b_pw2_w + blk*H_*HID_; const float* p2b = b_pw2_b + blk*H_;
      dwconv_ln4<<<(int)(Mc/4), 192, 0, stream>>>(h_c, dww, dwb, lnw, lnb, yln_c);
      gemm_t64<1><<<dim3(gmx, 6), 256, 0, stream>>>(yln_c, p1w, p1b,
                                                    y1_c, nullptr, nullptr, HID_, H_);
      grn_stats_kernel<<<Bc, 384, 0, stream>>>(y1_c, gg, scaleB);
      gemm_t64<2><<<dim3(gmx, 3), 256, 0, stream>>>(y1_c, p2w, p2b,
                                                    h_c, scaleB, gb, H_, HID_);
    }
    // 3. output LN -> h_seq, save last-t rows
    out_ln_kernel<<<(int)Mc, 192, 0, stream>>>(h_c, out_ln_w, out_ln_b, yln_c, hlast, ch*Bc);
    // 4. Kalman projection + wide transcendental prep + FMA-only scan
    gemm_t64<0><<<dim3(gmx, 1), 256, 0, stream>>>(yln_c, w_pad, b_pad,
                                                  rpraw, nullptr, nullptr, 64, H_);
    kalman_prep_kernel<<<(int)((Mc*32+255)/256), 256, 0, stream>>>(rpraw, rp_c, (int)Mc);
    kalman_scan_kernel<<<(Bc+3)/4, 64, 0, stream>>>(x_c, rp_c, xpost, ch*Bc, Bc);
  }
  // 5. GRU rollout: 64 blocks x 768 threads, 4-way split-K, quarter-owns-batch tail
  rollout_kernel<<<B_/BPB, RT_, 0, stream>>>(hlast, xpost, wT1, roll_in_b, wPack,
                                             gru_bih, gru_bhh, roll_ln_w, roll_ln_b,
                                             fc_rp_r_w, fc_rp_r_b, out);
  (void)in_sizes; (void)n_in; (void)out_size; (void)ws_size;
}

// Round 2
// 2726.426 us; speedup vs baseline: 1.2517x; 1.0257x over previous
//
#include <hip/hip_runtime.h>
#include <cstdint>
#include <cstddef>

#define B_    256
#define Q_    512
#define D_    32
#define H_    192
#define HID_  384
#define INCH_ 96
#define M_    (B_*Q_)    // 131072
#define WOUT_ 64
#define BPB   2          // batches per rollout block
#define RT_   768        // rollout threads: 4 quarters x 192, 12 waves
#define PI_F  3.14159265358979323846f

typedef unsigned int uint_t;

__device__ __forceinline__ float sigm(float x){ return 1.f/(1.f+expf(-x)); }
__device__ __forceinline__ float gelu_exact(float x){ return 0.5f*x*(1.f+erff(x*0.7071067811865475f)); }

// ---------------- features: [x, dy, ddy] ----------------
__global__ void feats_kernel(const float* __restrict__ x, float* __restrict__ feats, int nrows){
  int idx = blockIdx.x*256 + threadIdx.x;
  if (idx >= nrows*32) return;
  int d  = idx & 31;
  int bt = idx >> 5;
  int t  = bt & 511;
  const float* xr = x + (size_t)bt*D_;
  float xc  = xr[d];
  float xm1 = (t>0) ? xr[d - D_]   : 0.f;
  float xm2 = (t>1) ? xr[d - 2*D_] : 0.f;
  float dy   = (t>0) ? xc - xm1   : 0.f;
  float dym1 = (t>1) ? xm1 - xm2  : 0.f;
  float ddy  = (t>0) ? dy - dym1  : 0.f;
  float* fr = feats + (size_t)bt*INCH_;
  fr[d] = xc; fr[D_+d] = dy; fr[2*D_+d] = ddy;
}

// ---------------- 64x64x8 fp32 tiled GEMM, 4 blocks/CU ----------------
// MODE 0: out = acc+bias ; MODE 1: out = gelu(acc+bias) ; MODE 2: A affine, C += acc+bias
template<int MODE>
__global__ __launch_bounds__(256,4) void gemm_t64(
    const float* __restrict__ Af,
    const float* __restrict__ W,  const float* __restrict__ bias,
    float* __restrict__ Cf,
    const float* __restrict__ scale, const float* __restrict__ grnb,
    int N, int K)
{
  __shared__ float As[8][64];
  __shared__ float Bs[8][64];
  const int tid = threadIdx.x;
  const int bm = blockIdx.x*64, bn = blockIdx.y*64;
  const int tx = tid & 15, ty = tid >> 4;
  const int lrow = (tid & 127) >> 1, lk = (tid & 1)*4;
  const bool isA = tid < 128;
  const float* srow = (MODE==2) ? (scale + (size_t)(bm>>9)*HID_) : nullptr;

  float acc[4][4];
  #pragma unroll
  for (int i=0;i<4;i++)
    #pragma unroll
    for (int j=0;j<4;j++) acc[i][j]=0.f;

  const float* gsrc = isA ? (Af + (size_t)(bm+lrow)*K) : (W + (size_t)(bn+lrow)*K);

  for (int k0=0;k0<K;k0+=8){
    float4 v = *(const float4*)(gsrc + k0 + lk);
    if (MODE==2 && isA){
      int c = k0+lk;
      float4 sc = *(const float4*)(srow+c);
      float4 gb = *(const float4*)(grnb+c);
      v.x = v.x*sc.x+gb.x; v.y = v.y*sc.y+gb.y;
      v.z = v.z*sc.z+gb.z; v.w = v.w*sc.w+gb.w;
    }
    if (isA){
      As[lk+0][lrow]=v.x; As[lk+1][lrow]=v.y; As[lk+2][lrow]=v.z; As[lk+3][lrow]=v.w;
    } else {
      Bs[lk+0][lrow]=v.x; Bs[lk+1][lrow]=v.y; Bs[lk+2][lrow]=v.z; Bs[lk+3][lrow]=v.w;
    }
    __syncthreads();
    #pragma unroll
    for (int kk=0;kk<8;kk++){
      float4 a = *(const float4*)&As[kk][ty*4];
      float4 b = *(const float4*)&Bs[kk][tx*4];
      float ar[4] = {a.x,a.y,a.z,a.w};
      #pragma unroll
      for (int i=0;i<4;i++){
        acc[i][0] += ar[i]*b.x; acc[i][1] += ar[i]*b.y;
        acc[i][2] += ar[i]*b.z; acc[i][3] += ar[i]*b.w;
      }
    }
    __syncthreads();
  }

  const int o0 = bn + tx*4;
  float4 b0 = *(const float4*)(bias + o0);
  #pragma unroll
  for (int i=0;i<4;i++){
    int m = bm + ty*4 + i;
    if (MODE==0){
      float4 v; v.x=acc[i][0]+b0.x; v.y=acc[i][1]+b0.y; v.z=acc[i][2]+b0.z; v.w=acc[i][3]+b0.w;
      *(float4*)(Cf + (size_t)m*N + o0) = v;
    } else if (MODE==1){
      float4 v;
      v.x = gelu_exact(acc[i][0]+b0.x); v.y = gelu_exact(acc[i][1]+b0.y);
      v.z = gelu_exact(acc[i][2]+b0.z); v.w = gelu_exact(acc[i][3]+b0.w);
      *(float4*)(Cf + (size_t)m*N + o0) = v;
    } else {
      float4 old = *(const float4*)(Cf + (size_t)m*N + o0);
      float4 v; v.x=old.x+acc[i][0]+b0.x; v.y=old.y+acc[i][1]+b0.y;
      v.z=old.z+acc[i][2]+b0.z; v.w=old.w+acc[i][3]+b0.w;
      *(float4*)(Cf + (size_t)m*N + o0) = v;
    }
  }
}

// ---------------- depthwise conv (k=9, edge pad) + LN, 4 timesteps per block ----------------
__global__ __launch_bounds__(192) void dwconv_ln4(
  const float* __restrict__ h, const float* __restrict__ dww, const float* __restrict__ dwb,
  const float* __restrict__ lnw, const float* __restrict__ lnb, float* __restrict__ yln)
{
  __shared__ float sh[12][192];
  __shared__ float rs_[192], rq_[192], st[2];
  const int c  = threadIdx.x;
  const int t0 = (blockIdx.x & 127) * 4;
  const size_t base = (size_t)(blockIdx.x >> 7) * Q_ * H_;
  #pragma unroll
  for (int r=0;r<12;r++){
    int tt = t0 - 4 + r; tt = tt<0?0:(tt>511?511:tt);
    sh[r][c] = h[base + (size_t)tt*H_ + c];
  }
  float w[9];
  #pragma unroll
  for (int k=0;k<9;k++) w[k] = dww[c*9+k];
  const float dbias = dwb[c], lw = lnw[c], lb = lnb[c];
  __syncthreads();
  for (int i=0;i<4;i++){
    float acc = dbias;
    #pragma unroll
    for (int k=0;k<9;k++) acc += w[k]*sh[i+k][c];
    rs_[c]=acc; rq_[c]=acc*acc;
    __syncthreads();
    if (c < 64){
      float s = rs_[c]+rs_[c+64]+rs_[c+128];
      float q = rq_[c]+rq_[c+64]+rq_[c+128];
      #pragma unroll
      for (int off=32; off>0; off>>=1){ s += __shfl_down(s,off); q += __shfl_down(q,off); }
      if (c==0){ st[0]=s; st[1]=q; }
    }
    __syncthreads();
    float mean = st[0]*(1.f/H_);
    float var  = st[1]*(1.f/H_) - mean*mean;
    float r = rsqrtf(var + 1e-5f);
    yln[base + (size_t)(t0+i)*H_ + c] = (acc-mean)*r*lw + lb;
  }
}

// ---------------- output LayerNorm (+ save last-timestep row) ----------------
__global__ __launch_bounds__(192) void out_ln_kernel(
  const float* __restrict__ h, const float* __restrict__ lnw, const float* __restrict__ lnb,
  float* __restrict__ o, float* __restrict__ hlast, int b0)
{
  __shared__ float rs_[192], rq_[192], st[2];
  const int c  = threadIdx.x;
  const int bt = blockIdx.x;
  float v = h[(size_t)bt*H_ + c];
  rs_[c]=v; rq_[c]=v*v;
  __syncthreads();
  if (c < 64){
    float s = rs_[c]+rs_[c+64]+rs_[c+128];
    float q = rq_[c]+rq_[c+64]+rq_[c+128];
    #pragma unroll
    for (int off=32; off>0; off>>=1){ s += __shfl_down(s,off); q += __shfl_down(q,off); }
    if (c==0){ st[0]=s; st[1]=q; }
  }
  __syncthreads();
  float mean = st[0]*(1.f/H_);
  float var  = st[1]*(1.f/H_) - mean*mean;
  float r = rsqrtf(var + 1e-5f);
  float res = (v-mean)*r*lnw[c] + lnb[c];
  o[(size_t)bt*H_ + c] = res;
  if ((bt & 511) == 511) hlast[(size_t)(b0 + (bt>>9))*H_ + c] = res;
}

// ---------------- GRN stats ----------------
__global__ __launch_bounds__(384) void grn_stats_kernel(
  const float* __restrict__ y1, const float* __restrict__ grn_g, float* __restrict__ scale)
{
  __shared__ float r[384];
  const int c = threadIdx.x;
  const int b = blockIdx.x;
  const float* p = y1 + (size_t)b*Q_*HID_ + c;
  float s = 0.f;
  #pragma unroll 8
  for (int t=0;t<Q_;t++){ float v = p[(size_t)t*HID_]; s += v*v; }
  float gx = sqrtf(s);
  r[c] = gx;
  __syncthreads();
  if (c < 64){
    float v = r[c]+r[c+64]+r[c+128]+r[c+192]+r[c+256]+r[c+320];
    #pragma unroll
    for (int off=32; off>0; off>>=1) v += __shfl_down(v,off);
    if (c==0) r[0]=v;
  }
  __syncthreads();
  float mean = r[0]*(1.f/HID_);
  scale[(size_t)b*HID_ + c] = 1.f + grn_g[c]*gx/(mean + 1e-6f);
}

// ---------------- pack fc_rp / fc_gain into padded (64,192) W ----------------
__global__ void pack_w_kernel(const float* __restrict__ frw, const float* __restrict__ frb,
                              const float* __restrict__ fgw, const float* __restrict__ fgb,
                              float* __restrict__ w_pad, float* __restrict__ b_pad)
{
  int idx = blockIdx.x*256 + threadIdx.x;
  if (idx >= 64*192) return;
  int o = idx / 192, k = idx % 192;
  float v = 0.f;
  if (o < 2) v = frw[o*192+k]; else if (o < 34) v = fgw[(o-2)*192+k];
  w_pad[idx] = v;
  if (k == 0){
    float bv = 0.f;
    if (o < 2) bv = frb[o]; else if (o < 34) bv = fgb[o-2];
    b_pad[o] = bv;
  }
}

// ---------------- wide Kalman prep ----------------
__global__ void kalman_prep_kernel(const float* __restrict__ raw, float* __restrict__ rp, int nrows){
  int idx = blockIdx.x*256 + threadIdx.x;
  if (idx >= nrows*32) return;
  int d  = idx & 31;
  int bt = idx >> 5;
  const float* r = raw + (size_t)bt*64;
  float* o = rp + (size_t)bt*34;
  o[2+d] = sigm(r[2+d]);
  if (d==0){
    float rho = 1.25f*sigm(r[0]);
    float phi = PI_F * tanhf(r[1]);
    o[0] = rho*cosf(phi);
    o[1] = rho*sinf(phi);
  }
}

// ---------------- sequential Kalman scan (FMA-only) ----------------
__global__ __launch_bounds__(64) void kalman_scan_kernel(
  const float* __restrict__ x_c, const float* __restrict__ rp, float* __restrict__ xpost,
  int b0, int Bc)
{
  const int lane = threadIdx.x;
  const int bl = blockIdx.x*4 + (lane>>4);
  if (bl >= Bc) return;
  const int m = lane & 15;
  const float* xb  = x_c + (size_t)bl*Q_*D_;
  const float* rpb = rp  + (size_t)bl*Q_*34;
  float re = xb[m], im = xb[16+m];
  for (int t=0;t<Q_;t++){
    const float* r = rpb + (size_t)t*34;
    float rc = r[0], rs = r[1];
    float g0 = r[2+m], g1 = r[18+m];
    float y0 = xb[(size_t)t*D_ + m], y1v = xb[(size_t)t*D_ + 16 + m];
    float pr  = rc*re - rs*im;
    float pim = rs*re + rc*im;
    re = pr  + g0*(y0  - pr);
    im = pim + g1*(y1v - pim);
  }
  xpost[(b0+bl)*D_ + m] = re;
  xpost[(b0+bl)*D_ + 16 + m] = im;
}

// ---------------- rollout weight prep: wT1[k][o] + packed [k][o][8] gate block ----------------
__global__ void prep_rollout_kernel(const float* __restrict__ riw, const float* __restrict__ wih,
                                    const float* __restrict__ whh,
                                    float* __restrict__ wT1, float* __restrict__ wPack)
{
  int idx = blockIdx.x*256 + threadIdx.x;
  if (idx < 224*192){
    int o = idx % 192, k = idx / 192;
    wT1[idx] = riw[o*224 + k];
    return;
  }
  idx -= 224*192;
  if (idx < 192*192){
    int o = idx % 192, k = idx / 192;
    float* w = wPack + ((size_t)k*192 + o)*8;
    w[0] = wih[(0*192+o)*192 + k];
    w[1] = wih[(1*192+o)*192 + k];
    w[2] = wih[(2*192+o)*192 + k];
    w[3] = whh[(0*192+o)*192 + k];
    w[4] = whh[(1*192+o)*192 + k];
    w[5] = whh[(2*192+o)*192 + k];
    w[6] = 0.f; w[7] = 0.f;
  }
}

// ---------------- GRU rollout v3: BPB=2, 128 blocks, 768 threads ----------------
// - wT1 (phase-A weights) live in 56 registers per thread, loaded once (step-invariant).
// - Single fused reduction per step: sums {pre, pre^2, pre*u0, pre*u1} where u=lnw*frw;
//   rho/phi projections computed analytically from LN stats (no 2nd reduce, no hn pass).
// - LN-update (quarters 0/1) and Kalman-rotate (quarters 2/3) run concurrently.
// - 5 barriers/step (was 7).
__global__ __launch_bounds__(RT_,3) void rollout_kernel(
  const float* __restrict__ hlast, const float* __restrict__ xpost,
  const float* __restrict__ wT1,  const float* __restrict__ rib_,
  const float* __restrict__ wPack,
  const float* __restrict__ bih,  const float* __restrict__ bhh,
  const float* __restrict__ lnw,  const float* __restrict__ lnb,
  const float* __restrict__ frw,  const float* __restrict__ frb,
  float* __restrict__ out)
{
  const int tid = threadIdx.x;
  const int q   = tid / 192;        // quarter 0..3 (wave-aligned: 192 = 3 waves)
  const int o   = tid - q*192;      // channel 0..191
  const int bb  = blockIdx.x*BPB;

  __shared__ float hT[192][2];      // h state, batch-major
  __shared__ float xT[192][2];      // x = tanh(W1 [h;c]), batch-major
  __shared__ float cT[32][2];       // curr (Kalman state), batch-major
  __shared__ float pA[4][2][192];   // phase-A partials [quarter][batch][o]
  __shared__ float pB[4][12][192];  // phase-B partials [quarter][batch*6+gate][o]
  __shared__ float rsum[2][3][4];   // [batch][wave][S1,S2,S3,S4]

  // ---- init state ----
  if (q < 2){
    hT[o][q] = hlast[(size_t)(bb+q)*H_ + o];
    if (o < 32) cT[o][q] = xpost[(bb+q)*D_ + o];
  }

  const float w_ln = lnw[o], b_ln = lnb[o];
  const float fr0  = frw[o], fr1  = frw[192+o];
  const float fb0 = frb[0],  fb1 = frb[1];
  const float bi0 = bih[o], bi1 = bih[192+o], bi2 = bih[384+o];
  const float bh0 = bhh[o], bh1 = bhh[192+o], bh2 = bhh[384+o];
  const float rib = rib_[o];
  const float u0 = w_ln*fr0, u1 = w_ln*fr1;      // for fused projection
  const float t0c = b_ln*fr0, t1c = b_ln*fr1;

  // ---- phase-A weights in registers (step-invariant) ----
  float wreg[56];
  if (q < 3){
    const int kb = 56*q;
    #pragma unroll
    for (int i=0;i<56;i++) wreg[i] = wT1[(kb+i)*192+o];
  } else {
    #pragma unroll
    for (int i=0;i<24;i++) wreg[i] = wT1[(168+i)*192+o];
    #pragma unroll
    for (int i=0;i<32;i++) wreg[24+i] = wT1[(192+i)*192+o];
  }

  // ---- one-time constants: C0=sum(u0), C1=sum(u1), B0s=sum(lnb*fr0), B1s=sum(lnb*fr1) ----
  {
    float c0=u0, c1=u1, k0=t0c, k1=t1c;
    #pragma unroll
    for (int off=32; off>0; off>>=1){
      c0 += __shfl_down(c0,off); c1 += __shfl_down(c1,off);
      k0 += __shfl_down(k0,off); k1 += __shfl_down(k1,off);
    }
    if (q==0 && (o&63)==0){
      int w = o>>6;
      rsum[0][w][0]=c0; rsum[0][w][1]=c1; rsum[0][w][2]=k0; rsum[0][w][3]=k1;
    }
  }
  __syncthreads();
  const float C0 = rsum[0][0][0]+rsum[0][1][0]+rsum[0][2][0];
  const float C1 = rsum[0][0][1]+rsum[0][1][1]+rsum[0][2][1];
  const float K0 = rsum[0][0][2]+rsum[0][1][2]+rsum[0][2][2] + fb0;
  const float K1 = rsum[0][0][3]+rsum[0][1][3]+rsum[0][2][3] + fb1;

  for (int s=0; s<WOUT_; s++){
    // ---- phase A: partial x = W1 @ [h;c], K=224 split 4-way, weights in regs ----
    float a0=0.f, a1=0.f;
    if (q < 3){
      const int kb = 56*q;
      #pragma unroll
      for (int i=0;i<56;i++){
        float2 h2 = *(const float2*)&hT[kb+i][0];
        a0 += wreg[i]*h2.x; a1 += wreg[i]*h2.y;
      }
    } else {
      #pragma unroll
      for (int i=0;i<24;i++){
        float2 h2 = *(const float2*)&hT[168+i][0];
        a0 += wreg[i]*h2.x; a1 += wreg[i]*h2.y;
      }
      #pragma unroll
      for (int i=0;i<32;i++){
        float2 c2 = *(const float2*)&cT[i][0];
        a0 += wreg[24+i]*c2.x; a1 += wreg[24+i]*c2.y;
      }
    }
    pA[q][0][o]=a0; pA[q][1][o]=a1;
    __syncthreads();

    // ---- x combine: quarter j (<2) owns batch j ----
    if (q < 2){
      xT[o][q] = tanhf(rib + pA[0][q][o] + pA[1][q][o] + pA[2][q][o] + pA[3][q][o]);
    }
    __syncthreads();

    // ---- phase B: partial gates, K=192 split 4-way (48 each) ----
    float accx[2][3] = {{0.f,0.f,0.f},{0.f,0.f,0.f}};
    float acch[2][3] = {{0.f,0.f,0.f},{0.f,0.f,0.f}};
    {
      const int kb2 = 48*q;
      #pragma unroll 4
      for (int i=0;i<48;i++){
        const int k = kb2+i;
        const float4* wp = (const float4*)(wPack + ((size_t)k*192 + o)*8);
        const float4 wA = wp[0];
        const float4 wB = wp[1];
        const float2 xx = *(const float2*)&xT[k][0];
        const float2 hh = *(const float2*)&hT[k][0];
        accx[0][0] += wA.x*xx.x; accx[0][1] += wA.y*xx.x; accx[0][2] += wA.z*xx.x;
        accx[1][0] += wA.x*xx.y; accx[1][1] += wA.y*xx.y; accx[1][2] += wA.z*xx.y;
        acch[0][0] += wA.w*hh.x; acch[0][1] += wB.x*hh.x; acch[0][2] += wB.y*hh.x;
        acch[1][0] += wA.w*hh.y; acch[1][1] += wB.x*hh.y; acch[1][2] += wB.y*hh.y;
      }
    }
    #pragma unroll
    for (int j=0;j<2;j++){
      #pragma unroll
      for (int g=0;g<3;g++){
        pB[q][j*6+g][o]   = accx[j][g];
        pB[q][j*6+3+g][o] = acch[j][g];
      }
    }
    __syncthreads();

    // ---- gate combine + fused 4-sum wave reduction (quarters 0/1 own batch q) ----
    float pre = 0.f;
    if (q < 2){
      const int g6 = q*6;
      float P0 = bi0 + pB[0][g6+0][o]+pB[1][g6+0][o]+pB[2][g6+0][o]+pB[3][g6+0][o];
      float P1 = bi1 + pB[0][g6+1][o]+pB[1][g6+1][o]+pB[2][g6+1][o]+pB[3][g6+1][o];
      float P2 = bi2 + pB[0][g6+2][o]+pB[1][g6+2][o]+pB[2][g6+2][o]+pB[3][g6+2][o];
      float Q0 = bh0 + pB[0][g6+3][o]+pB[1][g6+3][o]+pB[2][g6+3][o]+pB[3][g6+3][o];
      float Q1 = bh1 + pB[0][g6+4][o]+pB[1][g6+4][o]+pB[2][g6+4][o]+pB[3][g6+4][o];
      float Q2 = bh2 + pB[0][g6+5][o]+pB[1][g6+5][o]+pB[2][g6+5][o]+pB[3][g6+5][o];
      float rg = sigm(P0+Q0), zz = sigm(P1+Q1);
      float nn = tanhf(P2 + rg*Q2);
      pre = (1.f-zz)*nn + zz*hT[o][q];
      float s1 = pre, s2 = pre*pre, s3 = pre*u0, s4 = pre*u1;
      #pragma unroll
      for (int off=32; off>0; off>>=1){
        s1 += __shfl_down(s1,off); s2 += __shfl_down(s2,off);
        s3 += __shfl_down(s3,off); s4 += __shfl_down(s4,off);
      }
      if ((o&63)==0){
        int w = o>>6;
        rsum[q][w][0]=s1; rsum[q][w][1]=s2; rsum[q][w][2]=s3; rsum[q][w][3]=s4;
      }
    }
    __syncthreads();

    // ---- concurrent tail: LN update (q<2) || Kalman rotate (q>=2, o<16) ----
    if (q < 2){
      float S1 = rsum[q][0][0]+rsum[q][1][0]+rsum[q][2][0];
      float S2 = rsum[q][0][1]+rsum[q][1][1]+rsum[q][2][1];
      float mu  = S1*(1.f/192.f);
      float var = S2*(1.f/192.f) - mu*mu;
      float r = rsqrtf(var+1e-5f);
      hT[o][q] = (pre-mu)*r*w_ln + b_ln;
    } else if (o < 16){
      const int j = q-2;
      float S1 = rsum[j][0][0]+rsum[j][1][0]+rsum[j][2][0];
      float S2 = rsum[j][0][1]+rsum[j][1][1]+rsum[j][2][1];
      float S3 = rsum[j][0][2]+rsum[j][1][2]+rsum[j][2][2];
      float S4 = rsum[j][0][3]+rsum[j][1][3]+rsum[j][2][3];
      float mu  = S1*(1.f/192.f);
      float var = S2*(1.f/192.f) - mu*mu;
      float r = rsqrtf(var+1e-5f);
      float proj0 = r*(S3 - mu*C0) + K0;
      float proj1 = r*(S4 - mu*C1) + K1;
      float rho = 1.25f*sigm(proj0);
      float phi = PI_F*tanhf(proj1);
      float rc = rho*cosf(phi), rs = rho*sinf(phi);
      float re = cT[o][j], im = cT[o+16][j];
      float nre = rc*re - rs*im;
      float nim = rs*re + rc*im;
      cT[o][j] = nre; cT[o+16][j] = nim;
      float* ob = out + ((size_t)(bb+j)*WOUT_ + s)*D_;
      ob[o] = nre; ob[o+16] = nim;
    }
    __syncthreads();
  }
}

// ---------------- host launch ----------------
extern "C" void kernel_launch(void* const* d_in, const int* in_sizes, int n_in,
                              void* d_out, int out_size, void* d_ws, size_t ws_size,
                              hipStream_t stream)
{
  const float* x_in     = (const float*)d_in[0];
  const float* inp_w    = (const float*)d_in[1];
  const float* inp_b    = (const float*)d_in[2];
  const float* b_dw_w   = (const float*)d_in[3];
  const float* b_dw_b   = (const float*)d_in[4];
  const float* b_ln_w   = (const float*)d_in[5];
  const float* b_ln_b   = (const float*)d_in[6];
  const float* b_pw1_w  = (const float*)d_in[7];
  const float* b_pw1_b  = (const float*)d_in[8];
  const float* b_grn_g  = (const float*)d_in[9];
  const float* b_grn_b  = (const float*)d_in[10];
  const float* b_pw2_w  = (const float*)d_in[11];
  const float* b_pw2_b  = (const float*)d_in[12];
  const float* out_ln_w = (const float*)d_in[13];
  const float* out_ln_b = (const float*)d_in[14];
  const float* fc_rp_w  = (const float*)d_in[15];
  const float* fc_rp_b  = (const float*)d_in[16];
  const float* fc_gain_w= (const float*)d_in[17];
  const float* fc_gain_b= (const float*)d_in[18];
  const float* roll_in_w= (const float*)d_in[19];
  const float* roll_in_b= (const float*)d_in[20];
  const float* gru_wih  = (const float*)d_in[21];
  const float* gru_whh  = (const float*)d_in[22];
  const float* gru_bih  = (const float*)d_in[23];
  const float* gru_bhh  = (const float*)d_in[24];
  const float* roll_ln_w= (const float*)d_in[25];
  const float* roll_ln_b= (const float*)d_in[26];
  const float* fc_rp_r_w= (const float*)d_in[27];
  const float* fc_rp_r_b= (const float*)d_in[28];
  float* out = (float*)d_out;

  // ---- adaptive chunking ----
  // per-row floats: h(192) + yln(192) + mid(384; feats/y1, then rpraw(64)+rp(34)) = 768
  // fixed tail: scaleB 98304 + w_pad 12288 + b_pad 64 + xpost 8192 + hlast 49152
  //           + wT1 43008 + wPack 294912 = 505920 ; + margin
  const size_t SMAL_FLOATS = 505920 + 4096;
  size_t ws_floats = ws_size / 4;
  int nchunk = 256;
  const int cand[9] = {1,2,4,8,16,32,64,128,256};
  for (int ci=0; ci<9; ci++){
    size_t Mc_try = (size_t)M_ / cand[ci];
    if (Mc_try*768 + SMAL_FLOATS <= ws_floats){ nchunk = cand[ci]; break; }
  }
  const int    Bc = B_ / nchunk;
  const size_t Mc = (size_t)Bc * Q_;

  float* ws    = (float*)d_ws;
  float* h_c   = ws;
  float* yln_c = h_c   + Mc*192;
  float* mid_c = yln_c + Mc*192;
  float* smal  = mid_c + Mc*384;

  float* feats_c = mid_c;
  float* y1_c    = mid_c;
  float* rpraw   = mid_c;                // Mc*64 (y1 dead by then)
  float* rp_c    = mid_c + Mc*64;        // Mc*34

  float* scaleB = smal;                  // Bc*384 (reserve 98304)
  float* w_pad  = smal + 98304;          // 64*192
  float* b_pad  = w_pad + 12288;         // 64
  float* xpost  = b_pad + 64;            // B_*32
  float* hlast  = xpost + 8192;          // B_*192
  float* wT1    = hlast + 49152;         // 224*192
  float* wPack  = wT1 + 43008;           // 192*192*8

  // one-time weight prep
  pack_w_kernel<<<(64*192+255)/256, 256, 0, stream>>>(fc_rp_w, fc_rp_b, fc_gain_w, fc_gain_b, w_pad, b_pad);
  prep_rollout_kernel<<<(224*192+192*192+255)/256, 256, 0, stream>>>(roll_in_w, gru_wih, gru_whh, wT1, wPack);

  const int gmx = (int)(Mc/64);
  for (int ch=0; ch<nchunk; ch++){
    const float* x_c = x_in + (size_t)ch*Mc*D_;
    // 1. features + input projection
    feats_kernel<<<(int)((Mc*32+255)/256), 256, 0, stream>>>(x_c, feats_c, (int)Mc);
    gemm_t64<0><<<dim3(gmx, 3), 256, 0, stream>>>(feats_c, inp_w, inp_b,
                                                  h_c, nullptr, nullptr, H_, INCH_);
    // 2. ConvNeXt blocks
    for (int blk = 0; blk < 2; blk++){
      const float* dww = b_dw_w + blk*H_*9;     const float* dwb = b_dw_b + blk*H_;
      const float* lnw = b_ln_w + blk*H_;       const float* lnb = b_ln_b + blk*H_;
      const float* p1w = b_pw1_w + blk*HID_*H_; const float* p1b = b_pw1_b + blk*HID_;
      const float* gg  = b_grn_g + blk*HID_;    const float* gb  = b_grn_b + blk*HID_;
      const float* p2w = b_pw2_w + blk*H_*HID_; const float* p2b = b_pw2_b + blk*H_;
      dwconv_ln4<<<(int)(Mc/4), 192, 0, stream>>>(h_c, dww, dwb, lnw, lnb, yln_c);
      gemm_t64<1><<<dim3(gmx, 6), 256, 0, stream>>>(yln_c, p1w, p1b,
                                                    y1_c, nullptr, nullptr, HID_, H_);
      grn_stats_kernel<<<Bc, 384, 0, stream>>>(y1_c, gg, scaleB);
      gemm_t64<2><<<dim3(gmx, 3), 256, 0, stream>>>(y1_c, p2w, p2b,
                                                    h_c, scaleB, gb, H_, HID_);
    }
    // 3. output LN -> h_seq, save last-t rows
    out_ln_kernel<<<(int)Mc, 192, 0, stream>>>(h_c, out_ln_w, out_ln_b, yln_c, hlast, ch*Bc);
    // 4. Kalman projection + wide transcendental prep + FMA-only scan
    gemm_t64<0><<<dim3(gmx, 1), 256, 0, stream>>>(yln_c, w_pad, b_pad,
                                                  rpraw, nullptr, nullptr, 64, H_);
    kalman_prep_kernel<<<(int)((Mc*32+255)/256), 256, 0, stream>>>(rpraw, rp_c, (int)Mc);
    kalman_scan_kernel<<<(Bc+3)/4, 64, 0, stream>>>(x_c, rp_c, xpost, ch*Bc, Bc);
  }
  // 5. GRU rollout v3: 128 blocks x 768 threads, BPB=2, reg-weights + fused reduction
  rollout_kernel<<<B_/BPB, RT_, 0, stream>>>(hlast, xpost, wT1, roll_in_b, wPack,
                                             gru_bih, gru_bhh, roll_ln_w, roll_ln_b,
                                             fc_rp_r_w, fc_rp_r_b, out);
  (void)in_sizes; (void)n_in; (void)out_size; (void)ws_size;
}